// Round 4
// baseline (136.503 us; speedup 1.0000x reference)
//
#include <hip/hip_runtime.h>
#include <hip/hip_bf16.h>

#define NROW 8192
#define DIM  128
#define NBLK 512            // 64 row-blocks x 8 column-splits
#define BIGF 1e30f

typedef __attribute__((ext_vector_type(8))) short bf16x8;
typedef __attribute__((ext_vector_type(4))) float f32x4;

// ws layout:
//   [0, 2 MB)      xbT  : fragment-major bf16 (A operand)
//   [2, 4 MB)      xbM2 : same layout, values scaled by -2 (B operand)
//   [4 MB, +64 KB) meta : uint2 { float bits sq[j], lbl[j] }
//   +32 KB         posb : u32 (d^2 bits, atomicMax)
//   +32 KB         negb : u32 (d^2 bits, atomicMin)
//   +16 B          counter
// fragment chunk: tile*2048 + ks*512 + lane*8 (ushorts); lane=quad*16+l15
// holds rows tile*16+l15, cols ks*32+quad*8..+7  (A and B layouts identical here)

__device__ __forceinline__ unsigned short f2bf(float f) {
    unsigned u = __float_as_uint(f);
    return (unsigned short)((u + 0x7fffu + ((u >> 16) & 1u)) >> 16);   // RNE
}

__global__ __launch_bounds__(256) void prep_kernel(const float* __restrict__ x,
                                                   const int* __restrict__ lbl,
                                                   unsigned short* __restrict__ xbT,
                                                   unsigned short* __restrict__ xbM2,
                                                   uint2* __restrict__ meta,
                                                   unsigned* __restrict__ posb,
                                                   unsigned* __restrict__ negb,
                                                   unsigned* __restrict__ counter,
                                                   float* __restrict__ out) {
    __shared__ unsigned short Al[32][136];   // stride 136: 16B-aligned rows, 2-way banks (free)
    __shared__ unsigned short Ml[32][136];
    __shared__ float sqp[32][8];

    const int b = blockIdx.x, t = threadIdx.x;
    const int gid = b * 256 + t;
    if (gid < NROW) { posb[gid] = 0u; negb[gid] = __float_as_uint(BIGF); }
    if (gid == 0)   { counter[0] = 0u; out[0] = 0.0f; }

    const int R0  = b * 32;                  // 32 rows per block
    const int r   = t >> 3;                  // 0..31
    const int seg = t & 7;                   // 16 floats per thread, coalesced
    const float* src = x + (size_t)(R0 + r) * DIM + seg * 16;

    float s = 0.0f;
    #pragma unroll
    for (int c4 = 0; c4 < 4; c4++) {
        float4 v = *(const float4*)(src + c4 * 4);
        s += v.x * v.x + v.y * v.y + v.z * v.z + v.w * v.w;
        uint2 ua, um;
        ua.x = (unsigned)f2bf(v.x) | ((unsigned)f2bf(v.y) << 16);
        ua.y = (unsigned)f2bf(v.z) | ((unsigned)f2bf(v.w) << 16);
        um.x = (unsigned)f2bf(-2.0f * v.x) | ((unsigned)f2bf(-2.0f * v.y) << 16);
        um.y = (unsigned)f2bf(-2.0f * v.z) | ((unsigned)f2bf(-2.0f * v.w) << 16);
        *(uint2*)&Al[r][seg * 16 + c4 * 4] = ua;
        *(uint2*)&Ml[r][seg * 16 + c4 * 4] = um;
    }
    sqp[r][seg] = s;
    __syncthreads();

    if (t < 32) {
        float ss = 0.0f;
        #pragma unroll
        for (int q = 0; q < 8; q++) ss += sqp[t][q];
        uint2 mv;
        mv.x = __float_as_uint(ss);
        mv.y = (unsigned)lbl[R0 + t];
        meta[R0 + t] = mv;
    }

    // fragment writes: 2 tiles/block; 256 threads cover one tile's 4 ks x 64 lanes
    const int ks = t >> 6, lane = t & 63;
    const int q = lane >> 4, l = lane & 15;
    #pragma unroll
    for (int tl = 0; tl < 2; tl++) {
        int row = tl * 16 + l, col = ks * 32 + q * 8;
        uint4 va = *(const uint4*)&Al[row][col];
        uint4 vm = *(const uint4*)&Ml[row][col];
        size_t off = (size_t)(R0 / 16 + tl) * 2048 + ks * 512 + lane * 8;
        *(uint4*)(xbT  + off) = va;
        *(uint4*)(xbM2 + off) = vm;
    }
}

__global__ __launch_bounds__(256, 2) void tri_mfma(const unsigned short* __restrict__ xbT,
                                                   const unsigned short* __restrict__ xbM2,
                                                   const uint2* __restrict__ meta,
                                                   unsigned* __restrict__ posb,
                                                   unsigned* __restrict__ negb,
                                                   unsigned* __restrict__ counter,
                                                   const float* __restrict__ margin,
                                                   float* __restrict__ out) {
    const int bid  = blockIdx.x;
    const int rb   = bid >> 3;           // 0..63
    const int jq   = bid & 7;            // 0..7
    const int i0   = rb * 128;
    const int t    = threadIdx.x;
    const int lane = t & 63;
    const int w    = t >> 6;
    const int wrow = (w >> 1) * 64;
    const int wcol = (w & 1) * 64;
    const int quad = lane >> 4;
    const int l15  = lane & 15;

    // A fragments resident in 64 VGPRs for the whole kernel
    bf16x8 A[4][4];
    {
        const int tbase = (i0 + wrow) >> 4;
        #pragma unroll
        for (int ti = 0; ti < 4; ti++)
            #pragma unroll
            for (int ks = 0; ks < 4; ks++)
                A[ti][ks] = *(const bf16x8*)(xbT + ((size_t)(tbase + ti) * 2048 + ks * 512 + lane * 8));
    }

    // row metadata: rows i0 + wrow + ti*16 + quad*4 + r
    float sqi[4][4]; int lbli[4][4];
    #pragma unroll
    for (int ti = 0; ti < 4; ti++) {
        int rbase = i0 + wrow + ti * 16 + quad * 4;
        uint4 m01 = *(const uint4*)(meta + rbase);
        uint4 m23 = *(const uint4*)(meta + rbase + 2);
        sqi[ti][0] = __uint_as_float(m01.x); lbli[ti][0] = (int)m01.y;
        sqi[ti][1] = __uint_as_float(m01.z); lbli[ti][1] = (int)m01.w;
        sqi[ti][2] = __uint_as_float(m23.x); lbli[ti][2] = (int)m23.y;
        sqi[ti][3] = __uint_as_float(m23.z); lbli[ti][3] = (int)m23.w;
    }

    float posm[4][4], negm[4][4];
    #pragma unroll
    for (int ti = 0; ti < 4; ti++)
        #pragma unroll
        for (int r = 0; r < 4; r++) { posm[ti][r] = -BIGF; negm[ti][r] = BIGF; }

    const int jbase = jq * (NROW / 8);
    const int dr    = l15 - quad * 4;    // diagonal element when dr == r (and ti == tj)

    #pragma unroll 1
    for (int jt = 0; jt < 8; jt++) {
        const int j0 = jbase + jt * 128;
        const int tb = (j0 + wcol) >> 4;
        const bool diag = (i0 + wrow) == (j0 + wcol);   // wave-uniform

        float sqj[4]; int lblj[4];
        #pragma unroll
        for (int tj = 0; tj < 4; tj++) {
            uint2 mv = meta[j0 + wcol + tj * 16 + l15];
            sqj[tj]  = __uint_as_float(mv.x);
            lblj[tj] = (int)mv.y;
        }

        // stream one column-tile at a time: live regs = A(64)+Bv(16)+acc(16)
        #pragma unroll
        for (int tj = 0; tj < 4; tj++) {
            bf16x8 Bv[4];
            #pragma unroll
            for (int ks = 0; ks < 4; ks++)
                Bv[ks] = *(const bf16x8*)(xbM2 + ((size_t)(tb + tj) * 2048 + ks * 512 + lane * 8));

            // accumulator seeded with sq_j (all 4 C-regs share col = l15)
            f32x4 acc[4];
            #pragma unroll
            for (int ti = 0; ti < 4; ti++)
                acc[ti] = (f32x4){sqj[tj], sqj[tj], sqj[tj], sqj[tj]};

            #pragma unroll
            for (int ks = 0; ks < 4; ks++)
                #pragma unroll
                for (int ti = 0; ti < 4; ti++)
                    acc[ti] = __builtin_amdgcn_mfma_f32_16x16x32_bf16(A[ti][ks], Bv[ks], acc[ti], 0, 0, 0);

            // acc now holds s = sq_j - 2*dot directly
            if (!diag) {
                #pragma unroll
                for (int ti = 0; ti < 4; ti++)
                    #pragma unroll
                    for (int r = 0; r < 4; r++) {
                        float s = acc[ti][r];
                        bool same = (lbli[ti][r] == lblj[tj]);
                        posm[ti][r] = fmaxf(posm[ti][r], same ? s : -BIGF);
                        negm[ti][r] = fminf(negm[ti][r], same ? BIGF : s);
                    }
            } else {
                #pragma unroll
                for (int ti = 0; ti < 4; ti++)
                    #pragma unroll
                    for (int r = 0; r < 4; r++) {
                        float s = acc[ti][r];
                        bool same = (lbli[ti][r] == lblj[tj]);
                        bool isd  = (ti == tj) && (dr == r);
                        posm[ti][r] = fmaxf(posm[ti][r], (same && !isd) ? s : -BIGF);
                        negm[ti][r] = fminf(negm[ti][r], same ? BIGF : s);
                    }
            }
        }
    }

    // reduce across the 16 column-lanes sharing each row; one atomic pair per row
    #pragma unroll
    for (int ti = 0; ti < 4; ti++)
        #pragma unroll
        for (int r = 0; r < 4; r++) {
            float p = posm[ti][r];
            float n = negm[ti][r];
            #pragma unroll
            for (int m = 8; m >= 1; m >>= 1) {
                p = fmaxf(p, __shfl_xor(p, m));
                n = fminf(n, __shfl_xor(n, m));
            }
            if (l15 == 0) {
                int row = i0 + wrow + ti * 16 + quad * 4 + r;
                float d2p = fmaxf(0.0f, sqi[ti][r] + p);   // no positive -> 0
                float d2n = fmaxf(0.0f, sqi[ti][r] + n);   // clamp bf16-noise negatives
                atomicMax(&posb[row], __float_as_uint(d2p));
                atomicMin(&negb[row], __float_as_uint(d2n));
            }
        }

    // ---- fused finalization: last block computes the loss ----
    __threadfence();                      // release my atomics
    __shared__ unsigned lastflag;
    __shared__ float wsum[4];
    __syncthreads();
    if (t == 0) {
        unsigned prev = __hip_atomic_fetch_add(counter, 1u, __ATOMIC_ACQ_REL, __HIP_MEMORY_SCOPE_AGENT);
        lastflag = (prev == NBLK - 1) ? 1u : 0u;
    }
    __syncthreads();
    if (lastflag) {
        __threadfence();                  // acquire
        float mg = margin[0];
        float loss = 0.0f;
        for (int row = t; row < NROW; row += 256) {
            unsigned pb = __hip_atomic_load(&posb[row], __ATOMIC_RELAXED, __HIP_MEMORY_SCOPE_AGENT);
            unsigned nb = __hip_atomic_load(&negb[row], __ATOMIC_RELAXED, __HIP_MEMORY_SCOPE_AGENT);
            float p  = sqrtf(__uint_as_float(pb));
            float ng = sqrtf(__uint_as_float(nb));
            loss += fmaxf(p - ng + mg, 0.0f);
        }
        #pragma unroll
        for (int o = 32; o > 0; o >>= 1) loss += __shfl_down(loss, o);
        if (lane == 0) wsum[w] = loss;
        __syncthreads();
        if (t == 0) out[0] = (wsum[0] + wsum[1] + wsum[2] + wsum[3]) * (1.0f / (float)NROW);
    }
}

extern "C" void kernel_launch(void* const* d_in, const int* in_sizes, int n_in,
                              void* d_out, int out_size, void* d_ws, size_t ws_size,
                              hipStream_t stream) {
    const float* x      = (const float*)d_in[0];
    const int*   lbl    = (const int*)d_in[1];
    const float* margin = (const float*)d_in[2];
    float* out = (float*)d_out;

    const size_t MAT = (size_t)NROW * DIM * 2;   // 2 MB per bf16 copy
    unsigned short* xbT  = (unsigned short*)d_ws;
    unsigned short* xbM2 = (unsigned short*)((char*)d_ws + MAT);
    uint2*    meta = (uint2*)((char*)d_ws + 2 * MAT);
    unsigned* posb = (unsigned*)((char*)meta + NROW * 8);
    unsigned* negb = posb + NROW;
    unsigned* counter = negb + NROW;

    prep_kernel<<<NROW / 32, 256, 0, stream>>>(x, lbl, xbT, xbM2, meta, posb, negb, counter, out);
    tri_mfma<<<NBLK, 256, 0, stream>>>(xbT, xbM2, meta, posb, negb, counter, margin, out);
}